// Round 2
// baseline (1870.568 us; speedup 1.0000x reference)
//
#include <hip/hip_runtime.h>
#include <hip/hip_bf16.h>
#include <math.h>

// ---------------- constants ----------------
#define BATCH   16
#define TFRM    4096          // frames per batch (= L)
#define DIM     512
#define ODIM    1026
#define KP      513           // ODIM/2
#define NFFT    1024
#define HOP     256
#define WINL    1024
#define PADC    384           // (WIN-HOP)/2
#define MROWS   (BATCH*TFRM)  // 65536
#define NPAD    1152          // ODIM padded to multiple of 128 (GEMM-friendly)
#define OUTLEN  1048576       // per-batch output samples
#define ENVLEN  1049344       // (T-1)*HOP + WIN
#define TWO_PI_OVER_N 0.006135923151542565f  // 2*pi/1024

typedef __bf16 bf16x8 __attribute__((ext_vector_type(8)));
typedef float  f32x4  __attribute__((ext_vector_type(4)));

__device__ __forceinline__ ushort f2bf(float f) {
  union { float f; unsigned u; } v; v.f = f;
  unsigned u = v.u;
  unsigned r = (u + 0x7FFFu + ((u >> 16) & 1u)) >> 16;
  return (ushort)r;
}
__device__ __forceinline__ float bf2f(ushort h) {
  union { unsigned u; float f; } v; v.u = ((unsigned)h) << 16;
  return v.f;
}

// ---------------- prep: x fp32 -> bf16 ----------------
__global__ void k_prep_x(const float4* __restrict__ x, ushort4* __restrict__ o, int n4) {
  int i = blockIdx.x * blockDim.x + threadIdx.x;
  int stride = gridDim.x * blockDim.x;
  for (; i < n4; i += stride) {
    float4 v = x[i];
    ushort4 r;
    r.x = f2bf(v.x); r.y = f2bf(v.y); r.z = f2bf(v.z); r.w = f2bf(v.w);
    o[i] = r;
  }
}

// ---------------- prep: W fp32 [1026][512] -> bf16 COLUMN-PERMUTED padded [1152][512]
// Output row j (= h column j): j=2k -> orig mag row k; j=2k+1 -> orig phase row 513+k.
__global__ void k_prep_w(const float* __restrict__ W, ushort* __restrict__ o) {
  int i = blockIdx.x * 256 + threadIdx.x;          // over 1152*512
  if (i >= NPAD * DIM) return;
  int r = i >> 9;                                  // permuted row
  int c = i & 511;
  ushort v = 0;
  if (r < ODIM) {
    int orig = (r >> 1) + (r & 1) * KP;
    v = f2bf(W[orig * DIM + c]);
  }
  o[i] = v;
}

// ---------------- basis: BasisT[n][j] bf16 (interleaved a/b layout to match h)
// frames[n] = win[n]/1024 * ( a0 + a512*(-1)^n + 2*sum_{k=1}^{511}(a_k cos - b_k sin) )
// j=2k: coeff for a_k ; j=2k+1: coeff for b_k
__global__ void k_basis(ushort* __restrict__ bas) {
  int n = blockIdx.x;
  float wn = 0.5f - 0.5f * cosf((float)n * TWO_PI_OVER_N);
  float sc = wn * (1.0f / 1024.0f);
  for (int j = threadIdx.x; j < NPAD; j += 256) {
    float v = 0.0f;
    if (j < ODIM) {
      int k = j >> 1;
      int r = (k * n) & 1023;                      // exact integer phase reduction
      if ((j & 1) == 0) {
        float c = cosf((float)r * TWO_PI_OVER_N);
        v = ((k == 0 || k == 512) ? 1.0f : 2.0f) * c;
      } else if (k != 0 && k != 512) {
        v = -2.0f * sinf((float)r * TWO_PI_OVER_N);
      }
    }
    bas[n * NPAD + j] = f2bf(v * sc);
  }
}

// ---------------- envelope: inv_env[s] = 1 / sum_t win^2[s-256t] ----------------
__global__ void k_env(float* __restrict__ inv_env) {
  int s = blockIdx.x * 256 + threadIdx.x;
  if (s >= ENVLEN) return;
  float e = 0.0f;
  int t0 = s >> 8;
#pragma unroll
  for (int q = 0; q < 4; ++q) {
    int t = t0 - q;
    if (t >= 0 && t < TFRM) {
      int n = (s & 255) + (q << 8);
      float w = 0.5f - 0.5f * cosf((float)n * TWO_PI_OVER_N);
      e += w * w;
    }
  }
  inv_env[s] = 1.0f / e;   // inf only in the cropped-away edge region (never read)
}

// ---------------- GEMM (B^T form): C[m][n] = sum_k A[m][k] * Bt[n][k], bf16 in/out, fp32 acc
// 128x128 tile, BK=32, 4 waves (2x2 of 64x64), double-buffered LDS via global_load_lds w16.
// XCD-chunked block swizzle (grid must be a multiple of 8).
// EPI=0: plain bf16 store. EPI=1: fused ISTFT-head activation on interleaved (mag,phase) cols.
template<int EPI>
__global__ __launch_bounds__(256) void k_gemm(const ushort* __restrict__ A, int lda,
                                              const ushort* __restrict__ Bt, int ldb,
                                              ushort* __restrict__ C, int ldc,
                                              int nbn, int K, const float* __restrict__ bias) {
  __shared__ __align__(16) ushort lds[2][2][128 * 32];
  const int tid  = threadIdx.x;
  // XCD-chunked swizzle: HW round-robins consecutive blockIdx across the 8 XCDs;
  // remap so each XCD runs a CONTIGUOUS chunk of logical blocks (A-panel stays in its L2).
  const int cpx  = gridDim.x >> 3;
  const int bid  = (blockIdx.x & 7) * cpx + (blockIdx.x >> 3);
  const int bm   = bid / nbn;
  const int bn   = bid - bm * nbn;
  const int lane = tid & 63;
  const int wv   = tid >> 6;
  const int wr   = (wv >> 1) * 64;
  const int wc   = (wv & 1) * 64;
  const int lr   = lane & 15;
  const int lk   = (lane >> 4) << 3;

  f32x4 acc[4][4] = {};

  auto stage = [&](const ushort* __restrict__ g, int ld, int row0, int k0, ushort* l) {
#pragma unroll
    for (int p = 0; p < 2; ++p) {
      int i = tid + p * 256;
      const ushort* gp = g + (size_t)(row0 + (i >> 2)) * ld + k0 + ((i & 3) << 3);
      ushort* lp = l + ((i >> 6) << 9);   // wave-uniform LDS base; HW scatters lane*16B
      __builtin_amdgcn_global_load_lds(
          (const __attribute__((address_space(1))) void*)gp,
          (__attribute__((address_space(3))) void*)lp, 16, 0, 0);
    }
  };

  const int NT = K >> 5;
  stage(A,  lda, bm * 128, 0, &lds[0][0][0]);
  stage(Bt, ldb, bn * 128, 0, &lds[0][1][0]);
  asm volatile("s_waitcnt vmcnt(0)" ::: "memory");
  __syncthreads();

  for (int t = 0; t < NT; ++t) {
    const int cur = t & 1;
    if (t + 1 < NT) {
      stage(A,  lda, bm * 128, (t + 1) << 5, &lds[cur ^ 1][0][0]);
      stage(Bt, ldb, bn * 128, (t + 1) << 5, &lds[cur ^ 1][1][0]);
    }
    const ushort* lA = &lds[cur][0][0];
    const ushort* lB = &lds[cur][1][0];
    bf16x8 aF[4], bF[4];
#pragma unroll
    for (int m = 0; m < 4; ++m)
      aF[m] = *(const bf16x8*)(lA + (wr + m * 16 + lr) * 32 + lk);
#pragma unroll
    for (int n = 0; n < 4; ++n)
      bF[n] = *(const bf16x8*)(lB + (wc + n * 16 + lr) * 32 + lk);
#pragma unroll
    for (int m = 0; m < 4; ++m)
#pragma unroll
      for (int n = 0; n < 4; ++n)
        acc[m][n] = __builtin_amdgcn_mfma_f32_16x16x32_bf16(aF[m], bF[n], acc[m][n], 0, 0, 0);
    asm volatile("s_waitcnt vmcnt(0)" ::: "memory");
    __syncthreads();
  }

  const int r0 = bm * 128 + wr + ((lane >> 4) << 2);
  const int c0 = bn * 128 + wc + lr;
#pragma unroll
  for (int m = 0; m < 4; ++m) {
    if (EPI == 0) {
#pragma unroll
      for (int j = 0; j < 4; ++j) {
        size_t rowoff = (size_t)(r0 + m * 16 + j) * ldc + c0;
#pragma unroll
        for (int n = 0; n < 4; ++n)
          C[rowoff + n * 16] = f2bf(acc[m][n][j]);
      }
    } else {
      // Fused activation: cols are interleaved (2k = mag_k, 2k+1 = phase_k).
      // Adjacent cols live in adjacent lanes of the fragment -> shfl_xor(1) pairs them.
#pragma unroll
      for (int n = 0; n < 4; ++n) {
        const int col = c0 + n * 16;
        const bool valid = col < ODIM;
        const float bs = valid ? bias[(col >> 1) + (col & 1) * KP] : 0.0f;
        const bool isPhaseLane = (col & 1);
#pragma unroll
        for (int j = 0; j < 4; ++j) {
          float v = acc[m][n][j] + bs;
          float pv = __shfl_xor(v, 1);
          float hm = isPhaseLane ? pv : v;
          float hp = isPhaseLane ? v : pv;
          float mag = fminf(expf(hm), 100.0f);
          float s, c;
          sincosf(hp, &s, &c);
          float outv = isPhaseLane ? mag * s : mag * c;
          C[(size_t)(r0 + m * 16 + j) * ldc + col] = valid ? f2bf(outv) : (ushort)0;
        }
      }
    }
  }
}

// ---------------- overlap-add + env division + crop ----------------
__global__ void k_oa(const ushort* __restrict__ frames, const float* __restrict__ inv_env,
                     float* __restrict__ out) {
  int u = blockIdx.x * 256 + threadIdx.x;   // 16 * 1048576 threads exactly
  int b  = u >> 20;
  int sp = u & (OUTLEN - 1);
  int s  = sp + PADC;
  int t0 = s >> 8;
  float acc = 0.0f;
#pragma unroll
  for (int q = 0; q < 4; ++q) {
    int t = t0 - q;
    if (t >= 0 && t < TFRM) {
      int n = (s & 255) + (q << 8);
      acc += bf2f(frames[(((size_t)(b << 12) + t) << 10) + n]);
    }
  }
  out[u] = acc * inv_env[s];
}

// ---------------- launch ----------------
extern "C" void kernel_launch(void* const* d_in, const int* in_sizes, int n_in,
                              void* d_out, int out_size, void* d_ws, size_t ws_size,
                              hipStream_t stream) {
  const float* x    = (const float*)d_in[0];
  const float* W    = (const float*)d_in[1];
  const float* bias = (const float*)d_in[2];
  float* out = (float*)d_out;
  char* ws = (char*)d_ws;

  // ws layout (bytes, all 256-aligned):
  //   [0, 134217728)            x_bf16 (67MB, dead after GEMM1)  ALIASED WITH frames (134MB)
  //   [134217728, 135397376)    Wp bf16 [1152][512] (column-permuted)
  //   [135397376, 137756672)    BasisT bf16 [1024][1152] (interleaved layout)
  //   [137756672, 141954048)    inv_env fp32 [1049344]
  //   [141954048, 292948992)    h bf16 [65536][1152] (post-activation, interleaved a/b)
  ushort* xbf    = (ushort*)(ws + 0);
  ushort* frames = (ushort*)(ws + 0);
  ushort* Wp     = (ushort*)(ws + 134217728);
  ushort* bas    = (ushort*)(ws + 135397376);
  float*  ienv   = (float*) (ws + 137756672);
  ushort* h      = (ushort*)(ws + 141954048);

  k_prep_x<<<8192, 256, 0, stream>>>((const float4*)x, (ushort4*)xbf, (BATCH * TFRM * DIM) / 4);
  k_prep_w<<<(NPAD * DIM) / 256, 256, 0, stream>>>(W, Wp);
  k_basis<<<NFFT, 256, 0, stream>>>(bas);
  k_env<<<(ENVLEN + 255) / 256, 256, 0, stream>>>(ienv);

  // GEMM1 + fused activation: h[65536][1152] = act( xbf[65536][512] . Wp^T + bias )
  k_gemm<1><<<(MROWS / 128) * (NPAD / 128), 256, 0, stream>>>(xbf, DIM, Wp, DIM, h, NPAD,
                                                              NPAD / 128, DIM, bias);

  // GEMM2: frames[65536][1024] = h[65536][1152] . BasisT[1024][1152]^T
  k_gemm<0><<<(MROWS / 128) * (NFFT / 128), 256, 0, stream>>>(h, NPAD, bas, NPAD, frames, NFFT,
                                                              NFFT / 128, NPAD, nullptr);

  // overlap-add, envelope normalize, crop
  k_oa<<<(BATCH * OUTLEN) / 256, 256, 0, stream>>>(frames, ienv, out);
}

// Round 4
// 433.575 us; speedup vs baseline: 4.3143x; 4.3143x over previous
//
#include <hip/hip_runtime.h>
#include <hip/hip_bf16.h>
#include <math.h>

// ---------------- constants ----------------
#define BATCH   16
#define TFRM    4096          // frames per batch (= L)
#define DIM     512
#define ODIM    1026
#define KP      513           // ODIM/2
#define NFFT    1024
#define HOP     256
#define WINL    1024
#define PADC    384           // (WIN-HOP)/2
#define MROWS   (BATCH*TFRM)  // 65536
#define NPAD    1152          // ODIM padded to multiple of 128 (GEMM-friendly)
#define OUTLEN  1048576       // per-batch output samples
#define ENVLEN  1049344       // (T-1)*HOP + WIN
#define TWO_PI_OVER_N 0.006135923151542565f  // 2*pi/1024
#define INV_TWO_PI    0.15915494309189535f   // 1/(2*pi)

typedef __bf16 bf16x8 __attribute__((ext_vector_type(8)));
typedef float  f32x4  __attribute__((ext_vector_type(4)));

__device__ __forceinline__ ushort f2bf(float f) {
  union { float f; unsigned u; } v; v.f = f;
  unsigned u = v.u;
  unsigned r = (u + 0x7FFFu + ((u >> 16) & 1u)) >> 16;
  return (ushort)r;
}
__device__ __forceinline__ float bf2f(ushort h) {
  union { unsigned u; float f; } v; v.u = ((unsigned)h) << 16;
  return v.f;
}
// Fast HW transcendentals (inline VALU, no libm calls / no scratch):
//   v_sin_f32 / v_cos_f32 take REVOLUTIONS; |p| < ~5 rad so fp32 mul is exact enough.
//   v_exp_f32 is 2^x -> exp(x) = exp2(x * log2(e)).
__device__ __forceinline__ float fast_sin(float x) {
  return __builtin_amdgcn_sinf(x * INV_TWO_PI);
}
__device__ __forceinline__ float fast_cos(float x) {
  return __builtin_amdgcn_cosf(x * INV_TWO_PI);
}
__device__ __forceinline__ float fast_exp(float x) {
  return __builtin_amdgcn_exp2f(x * 1.4426950408889634f);
}

// ---------------- prep: x fp32 -> bf16 ----------------
__global__ void k_prep_x(const float4* __restrict__ x, ushort4* __restrict__ o, int n4) {
  int i = blockIdx.x * blockDim.x + threadIdx.x;
  int stride = gridDim.x * blockDim.x;
  for (; i < n4; i += stride) {
    float4 v = x[i];
    ushort4 r;
    r.x = f2bf(v.x); r.y = f2bf(v.y); r.z = f2bf(v.z); r.w = f2bf(v.w);
    o[i] = r;
  }
}

// ---------------- prep: W fp32 [1026][512] -> bf16 COLUMN-PERMUTED padded [1152][512]
// Output row j (= h column j): j=2k -> orig mag row k; j=2k+1 -> orig phase row 513+k.
__global__ void k_prep_w(const float* __restrict__ W, ushort* __restrict__ o) {
  int i = blockIdx.x * 256 + threadIdx.x;          // over 1152*512
  if (i >= NPAD * DIM) return;
  int r = i >> 9;                                  // permuted row
  int c = i & 511;
  ushort v = 0;
  if (r < ODIM) {
    int orig = (r >> 1) + (r & 1) * KP;
    v = f2bf(W[orig * DIM + c]);
  }
  o[i] = v;
}

// ---------------- basis: BasisT[n][j] bf16 (interleaved a/b layout to match h)
// frames[n] = win[n]/1024 * ( a0 + a512*(-1)^n + 2*sum_{k=1}^{511}(a_k cos - b_k sin) )
// j=2k: coeff for a_k ; j=2k+1: coeff for b_k
__global__ void k_basis(ushort* __restrict__ bas) {
  int n = blockIdx.x;
  float wn = 0.5f - 0.5f * cosf((float)n * TWO_PI_OVER_N);
  float sc = wn * (1.0f / 1024.0f);
  for (int j = threadIdx.x; j < NPAD; j += 256) {
    float v = 0.0f;
    if (j < ODIM) {
      int k = j >> 1;
      int r = (k * n) & 1023;                      // exact integer phase reduction
      if ((j & 1) == 0) {
        float c = cosf((float)r * TWO_PI_OVER_N);
        v = ((k == 0 || k == 512) ? 1.0f : 2.0f) * c;
      } else if (k != 0 && k != 512) {
        v = -2.0f * sinf((float)r * TWO_PI_OVER_N);
      }
    }
    bas[n * NPAD + j] = f2bf(v * sc);
  }
}

// ---------------- envelope: inv_env[s] = 1 / sum_t win^2[s-256t] ----------------
__global__ void k_env(float* __restrict__ inv_env) {
  int s = blockIdx.x * 256 + threadIdx.x;
  if (s >= ENVLEN) return;
  float e = 0.0f;
  int t0 = s >> 8;
#pragma unroll
  for (int q = 0; q < 4; ++q) {
    int t = t0 - q;
    if (t >= 0 && t < TFRM) {
      int n = (s & 255) + (q << 8);
      float w = 0.5f - 0.5f * cosf((float)n * TWO_PI_OVER_N);
      e += w * w;
    }
  }
  inv_env[s] = 1.0f / e;   // inf only in the cropped-away edge region (never read)
}

// ---------------- GEMM (B^T form): C[m][n] = sum_k A[m][k] * Bt[n][k], bf16 in/out, fp32 acc
// 128x128 tile, BK=32, 4 waves (2x2 of 64x64), double-buffered LDS via global_load_lds w16.
// XCD-chunked block swizzle (grid must be a multiple of 8).
// EPI=0: plain bf16 store. EPI=1: fused ISTFT-head activation on interleaved (mag,phase) cols.
template<int EPI>
__global__ __launch_bounds__(256) void k_gemm(const ushort* __restrict__ A, int lda,
                                              const ushort* __restrict__ Bt, int ldb,
                                              ushort* __restrict__ C, int ldc,
                                              int nbn, int K, const float* __restrict__ bias) {
  __shared__ __align__(16) ushort lds[2][2][128 * 32];
  const int tid  = threadIdx.x;
  // XCD-chunked swizzle: HW round-robins consecutive blockIdx across the 8 XCDs;
  // remap so each XCD runs a CONTIGUOUS chunk of logical blocks (A-panel stays in its L2).
  const int cpx  = gridDim.x >> 3;
  const int bid  = (blockIdx.x & 7) * cpx + (blockIdx.x >> 3);
  const int bm   = bid / nbn;
  const int bn   = bid - bm * nbn;
  const int lane = tid & 63;
  const int wv   = tid >> 6;
  const int wr   = (wv >> 1) * 64;
  const int wc   = (wv & 1) * 64;
  const int lr   = lane & 15;
  const int lk   = (lane >> 4) << 3;

  f32x4 acc[4][4] = {};

  auto stage = [&](const ushort* __restrict__ g, int ld, int row0, int k0, ushort* l) {
#pragma unroll
    for (int p = 0; p < 2; ++p) {
      int i = tid + p * 256;
      const ushort* gp = g + (size_t)(row0 + (i >> 2)) * ld + k0 + ((i & 3) << 3);
      ushort* lp = l + ((i >> 6) << 9);   // wave-uniform LDS base; HW scatters lane*16B
      __builtin_amdgcn_global_load_lds(
          (const __attribute__((address_space(1))) void*)gp,
          (__attribute__((address_space(3))) void*)lp, 16, 0, 0);
    }
  };

  const int NT = K >> 5;
  stage(A,  lda, bm * 128, 0, &lds[0][0][0]);
  stage(Bt, ldb, bn * 128, 0, &lds[0][1][0]);
  asm volatile("s_waitcnt vmcnt(0)" ::: "memory");
  __syncthreads();

  for (int t = 0; t < NT; ++t) {
    const int cur = t & 1;
    if (t + 1 < NT) {
      stage(A,  lda, bm * 128, (t + 1) << 5, &lds[cur ^ 1][0][0]);
      stage(Bt, ldb, bn * 128, (t + 1) << 5, &lds[cur ^ 1][1][0]);
    }
    const ushort* lA = &lds[cur][0][0];
    const ushort* lB = &lds[cur][1][0];
    bf16x8 aF[4], bF[4];
#pragma unroll
    for (int m = 0; m < 4; ++m)
      aF[m] = *(const bf16x8*)(lA + (wr + m * 16 + lr) * 32 + lk);
#pragma unroll
    for (int n = 0; n < 4; ++n)
      bF[n] = *(const bf16x8*)(lB + (wc + n * 16 + lr) * 32 + lk);
#pragma unroll
    for (int m = 0; m < 4; ++m)
#pragma unroll
      for (int n = 0; n < 4; ++n)
        acc[m][n] = __builtin_amdgcn_mfma_f32_16x16x32_bf16(aF[m], bF[n], acc[m][n], 0, 0, 0);
    asm volatile("s_waitcnt vmcnt(0)" ::: "memory");
    __syncthreads();
  }

  const int r0 = bm * 128 + wr + ((lane >> 4) << 2);
  const int c0 = bn * 128 + wc + lr;
#pragma unroll
  for (int m = 0; m < 4; ++m) {
    if (EPI == 0) {
#pragma unroll
      for (int j = 0; j < 4; ++j) {
        size_t rowoff = (size_t)(r0 + m * 16 + j) * ldc + c0;
#pragma unroll
        for (int n = 0; n < 4; ++n)
          C[rowoff + n * 16] = f2bf(acc[m][n][j]);
      }
    } else {
      // Fused activation: cols are interleaved (2k = mag_k, 2k+1 = phase_k).
      // Adjacent cols live in adjacent lanes of the fragment -> shfl_xor(1) pairs them.
      // All transcendentals are single-VALU HW ops (v_exp/v_sin/v_cos) — no libm,
      // no scratch (round 2's sincosf/expf caused 8 GB of spill traffic).
#pragma unroll
      for (int n = 0; n < 4; ++n) {
        const int col = c0 + n * 16;
        const bool valid = col < ODIM;
        const float bs = valid ? bias[(col >> 1) + (col & 1) * KP] : 0.0f;
        const bool isPhaseLane = (col & 1);
#pragma unroll
        for (int j = 0; j < 4; ++j) {
          float v = acc[m][n][j] + bs;
          float pv = __shfl_xor(v, 1);
          float hm = isPhaseLane ? pv : v;
          float hp = isPhaseLane ? v : pv;
          float mag = fminf(fast_exp(hm), 100.0f);
          float outv = isPhaseLane ? mag * fast_sin(hp) : mag * fast_cos(hp);
          C[(size_t)(r0 + m * 16 + j) * ldc + col] = valid ? f2bf(outv) : (ushort)0;
        }
      }
    }
  }
}

// ---------------- overlap-add + env division + crop ----------------
__global__ void k_oa(const ushort* __restrict__ frames, const float* __restrict__ inv_env,
                     float* __restrict__ out) {
  int u = blockIdx.x * 256 + threadIdx.x;   // 16 * 1048576 threads exactly
  int b  = u >> 20;
  int sp = u & (OUTLEN - 1);
  int s  = sp + PADC;
  int t0 = s >> 8;
  float acc = 0.0f;
#pragma unroll
  for (int q = 0; q < 4; ++q) {
    int t = t0 - q;
    if (t >= 0 && t < TFRM) {
      int n = (s & 255) + (q << 8);
      acc += bf2f(frames[(((size_t)(b << 12) + t) << 10) + n]);
    }
  }
  out[u] = acc * inv_env[s];
}

// ---------------- launch ----------------
extern "C" void kernel_launch(void* const* d_in, const int* in_sizes, int n_in,
                              void* d_out, int out_size, void* d_ws, size_t ws_size,
                              hipStream_t stream) {
  const float* x    = (const float*)d_in[0];
  const float* W    = (const float*)d_in[1];
  const float* bias = (const float*)d_in[2];
  float* out = (float*)d_out;
  char* ws = (char*)d_ws;

  // ws layout (bytes, all 256-aligned):
  //   [0, 134217728)            x_bf16 (67MB, dead after GEMM1)  ALIASED WITH frames (134MB)
  //   [134217728, 135397376)    Wp bf16 [1152][512] (column-permuted)
  //   [135397376, 137756672)    BasisT bf16 [1024][1152] (interleaved layout)
  //   [137756672, 141954048)    inv_env fp32 [1049344]
  //   [141954048, 292948992)    h bf16 [65536][1152] (post-activation, interleaved a/b)
  ushort* xbf    = (ushort*)(ws + 0);
  ushort* frames = (ushort*)(ws + 0);
  ushort* Wp     = (ushort*)(ws + 134217728);
  ushort* bas    = (ushort*)(ws + 135397376);
  float*  ienv   = (float*) (ws + 137756672);
  ushort* h      = (ushort*)(ws + 141954048);

  k_prep_x<<<8192, 256, 0, stream>>>((const float4*)x, (ushort4*)xbf, (BATCH * TFRM * DIM) / 4);
  k_prep_w<<<(NPAD * DIM) / 256, 256, 0, stream>>>(W, Wp);
  k_basis<<<NFFT, 256, 0, stream>>>(bas);
  k_env<<<(ENVLEN + 255) / 256, 256, 0, stream>>>(ienv);

  // GEMM1 + fused activation: h[65536][1152] = act( xbf[65536][512] . Wp^T + bias )
  k_gemm<1><<<(MROWS / 128) * (NPAD / 128), 256, 0, stream>>>(xbf, DIM, Wp, DIM, h, NPAD,
                                                              NPAD / 128, DIM, bias);

  // GEMM2: frames[65536][1024] = h[65536][1152] . BasisT[1024][1152]^T
  k_gemm<0><<<(MROWS / 128) * (NFFT / 128), 256, 0, stream>>>(h, NPAD, bas, NPAD, frames, NFFT,
                                                              NFFT / 128, NPAD, nullptr);

  // overlap-add, envelope normalize, crop
  k_oa<<<(BATCH * OUTLEN) / 256, 256, 0, stream>>>(frames, ienv, out);
}

// Round 5
// 377.065 us; speedup vs baseline: 4.9609x; 1.1499x over previous
//
#include <hip/hip_runtime.h>
#include <hip/hip_bf16.h>
#include <math.h>

// ---------------- constants ----------------
#define BATCH   16
#define TFRM    4096          // frames per batch (= L)
#define DIM     512
#define ODIM    1026
#define KP      513           // ODIM/2
#define NFFT    1024
#define HOP     256
#define PADC    384           // (WIN-HOP)/2
#define MROWS   (BATCH*TFRM)  // 65536
#define NPAD    1152          // h stride (= GEMM2 K), multiple of 32
#define WROWS   1280          // GEMM1 logical N, multiple of 256
#define OUTLEN  1048576       // per-batch output samples
#define TWO_PI_OVER_N 0.006135923151542565f  // 2*pi/1024
#define INV_TWO_PI    0.15915494309189535f   // 1/(2*pi)

typedef __bf16 bf16x8 __attribute__((ext_vector_type(8)));
typedef float  f32x4  __attribute__((ext_vector_type(4)));

__device__ __forceinline__ ushort f2bf(float f) {
  union { float f; unsigned u; } v; v.f = f;
  unsigned u = v.u;
  unsigned r = (u + 0x7FFFu + ((u >> 16) & 1u)) >> 16;
  return (ushort)r;
}
__device__ __forceinline__ float bf2f(ushort h) {
  union { unsigned u; float f; } v; v.u = ((unsigned)h) << 16;
  return v.f;
}
// HW transcendentals (single VALU op each; v_sin/v_cos take revolutions).
__device__ __forceinline__ float fast_sin(float x) { return __builtin_amdgcn_sinf(x * INV_TWO_PI); }
__device__ __forceinline__ float fast_cos(float x) { return __builtin_amdgcn_cosf(x * INV_TWO_PI); }
__device__ __forceinline__ float fast_exp(float x) { return __builtin_amdgcn_exp2f(x * 1.4426950408889634f); }

#define BAR() do { asm volatile("" ::: "memory"); __builtin_amdgcn_s_barrier(); \
                   asm volatile("" ::: "memory"); } while (0)

// ---------------- prep: x fp32 -> bf16 ----------------
__global__ void k_prep_x(const float4* __restrict__ x, ushort4* __restrict__ o, int n4) {
  int i = blockIdx.x * blockDim.x + threadIdx.x;
  int stride = gridDim.x * blockDim.x;
  for (; i < n4; i += stride) {
    float4 v = x[i];
    ushort4 r;
    r.x = f2bf(v.x); r.y = f2bf(v.y); r.z = f2bf(v.z); r.w = f2bf(v.w);
    o[i] = r;
  }
}

// ---------------- prep: W fp32 [1026][512] -> bf16 COLUMN-PERMUTED padded [1280][512]
// Row j (= h column j): j=2k -> orig mag row k; j=2k+1 -> orig phase row 513+k.
__global__ void k_prep_w(const float* __restrict__ W, ushort* __restrict__ o) {
  int i = blockIdx.x * 256 + threadIdx.x;          // over 1280*512
  if (i >= WROWS * DIM) return;
  int r = i >> 9;
  int c = i & 511;
  ushort v = 0;
  if (r < ODIM) {
    int orig = (r >> 1) + (r & 1) * KP;
    v = f2bf(W[orig * DIM + c]);
  }
  o[i] = v;
}

// ---------------- basis: BasisT[n][j] bf16, interleaved (a,b) layout, stride NPAD ----------------
// frames[n] = win[n]/1024 * ( a0 + a512*(-1)^n + 2*sum_{k=1}^{511}(a_k cos - b_k sin) )
__global__ void k_basis(ushort* __restrict__ bas) {
  int n = blockIdx.x;
  float wn = 0.5f - 0.5f * cosf((float)n * TWO_PI_OVER_N);
  float sc = wn * (1.0f / 1024.0f);
  for (int j = threadIdx.x; j < NPAD; j += 256) {
    float v = 0.0f;
    if (j < ODIM) {
      int k = j >> 1;
      int r = (k * n) & 1023;                      // exact integer phase reduction
      if ((j & 1) == 0) {
        float c = cosf((float)r * TWO_PI_OVER_N);
        v = ((k == 0 || k == 512) ? 1.0f : 2.0f) * c;
      } else if (k != 0 && k != 512) {
        v = -2.0f * sinf((float)r * TWO_PI_OVER_N);
      }
    }
    bas[n * NPAD + j] = f2bf(v * sc);
  }
}

// ---------------- GEMM: C[m][n] = sum_k A[m][k]*Bt[n][k]  (bf16 in, fp32 acc)
// 256x256 tile, BK=32, 8 waves (2M x 4N), 512 threads, ring of 4 LDS buffers,
// prefetch distance 3 K-tiles, counted vmcnt(8) (never drained in main loop),
// granule-XOR LDS swizzle (inverse-swizzled global source + swizzled ds_read),
// raw s_barrier + setprio around MFMA clusters, XCD-chunked block swizzle.
// EPI=1: fused ISTFT-head activation on interleaved (mag,phase) columns.
template<int EPI>
__global__ __launch_bounds__(512, 2) void k_gemm(const ushort* __restrict__ A, int lda,
                                                 const ushort* __restrict__ Bt, int ldb,
                                                 ushort* __restrict__ C, int ldc,
                                                 int nbn, int NT, int ncol,
                                                 const float* __restrict__ bias) {
  // 4 bufs x (A 256x32 + B 256x32) ushorts = 128 KiB
  __shared__ ushort lds[4][2][8192];
  const int tid  = threadIdx.x;
  const int cpx  = gridDim.x >> 3;
  const int bid  = (blockIdx.x & 7) * cpx + (blockIdx.x >> 3);   // XCD-chunked
  const int bm   = bid / nbn;
  const int bn   = bid - bm * nbn;
  const int lane = tid & 63;
  const int wv   = tid >> 6;
  const int wr   = (wv >> 2) * 128;    // wave M-offset (2 M-halves)
  const int wc   = (wv & 3) * 64;      // wave N-offset (4 N-quarters)
  const int fr   = lane & 15;
  const int gq   = lane >> 4;          // K-granule of the fragment (0..3)

  // ---- staging pointers (thread i covers granule i and i+512 of each 256x32 tile) ----
  // LDS is written linearly by global_load_lds; the swizzle is applied by permuting
  // the GLOBAL source granule: gcol = (i&3) ^ ((i>>3)&3)  (= (i&3) ^ ((row>>1)&3)).
  const int swz  = ((tid & 3) ^ ((tid >> 3) & 3)) << 3;          // ushort offset
  const ushort* gA0 = A  + (size_t)(bm * 256 + (tid >> 2)) * lda + swz;
  const ushort* gA1 = gA0 + (size_t)128 * lda;
  const ushort* gB0 = Bt + (size_t)(bn * 256 + (tid >> 2)) * ldb + swz;
  const ushort* gB1 = gB0 + (size_t)128 * ldb;
  const int lofs = (tid & 448) * 8;    // wave-uniform LDS granule base (x8 ushorts)

  auto stage = [&](const ushort* g0, const ushort* g1, int S, ushort* dst) {
    const ushort* p0 = g0 + S * 32;
    const ushort* p1 = g1 + S * 32;
    __builtin_amdgcn_global_load_lds((const __attribute__((address_space(1))) void*)p0,
        (__attribute__((address_space(3))) void*)(dst + lofs), 16, 0, 0);
    __builtin_amdgcn_global_load_lds((const __attribute__((address_space(1))) void*)p1,
        (__attribute__((address_space(3))) void*)(dst + 4096 + lofs), 16, 0, 0);
  };
  // swizzled fragment read: logical (row, gq) lives at physical granule gq ^ ((row>>1)&3)
  auto frag = [&](const ushort* lb, int row) -> bf16x8 {
    return *(const bf16x8*)(lb + row * 32 + ((gq ^ ((row >> 1) & 3)) << 3));
  };

  f32x4 acc[8][4] = {};

  // ---- prologue: stage tiles 0,1,2 (12 loads/thread), wait for tile 0 ----
  stage(gA0, gA1, 0, &lds[0][0][0]);  stage(gB0, gB1, 0, &lds[0][1][0]);
  stage(gA0, gA1, 1, &lds[1][0][0]);  stage(gB0, gB1, 1, &lds[1][1][0]);
  stage(gA0, gA1, 2, &lds[2][0][0]);  stage(gB0, gB1, 2, &lds[2][1][0]);
  asm volatile("s_waitcnt vmcnt(8)" ::: "memory");
  BAR();

  auto tile = [&](int T, bool stg, bool w8) {
    const ushort* lA = &lds[T & 3][0][0];
    const ushort* lB = &lds[T & 3][1][0];
    bf16x8 aF[8], b0, b1;
    // ---- phase A: read A(m0-7), B(n0-1); stage A-tile of T+3; MFMA quadrant n0-1 ----
    if (stg) stage(gA0, gA1, T + 3, &lds[(T + 3) & 3][0][0]);
#pragma unroll
    for (int m = 0; m < 8; ++m) aF[m] = frag(lA, wr + m * 16 + fr);
    b0 = frag(lB, wc + fr);
    b1 = frag(lB, wc + 16 + fr);
    BAR();
    __builtin_amdgcn_s_setprio(1);
#pragma unroll
    for (int m = 0; m < 8; ++m) {
      acc[m][0] = __builtin_amdgcn_mfma_f32_16x16x32_bf16(aF[m], b0, acc[m][0], 0, 0, 0);
      acc[m][1] = __builtin_amdgcn_mfma_f32_16x16x32_bf16(aF[m], b1, acc[m][1], 0, 0, 0);
    }
    __builtin_amdgcn_s_setprio(0);
    BAR();
    // ---- phase B: read B(n2-3); stage B-tile of T+3; MFMA quadrant n2-3 ----
    if (stg) stage(gB0, gB1, T + 3, &lds[(T + 3) & 3][1][0]);
    b0 = frag(lB, wc + 32 + fr);
    b1 = frag(lB, wc + 48 + fr);
    BAR();
    __builtin_amdgcn_s_setprio(1);
#pragma unroll
    for (int m = 0; m < 8; ++m) {
      acc[m][2] = __builtin_amdgcn_mfma_f32_16x16x32_bf16(aF[m], b0, acc[m][2], 0, 0, 0);
      acc[m][3] = __builtin_amdgcn_mfma_f32_16x16x32_bf16(aF[m], b1, acc[m][3], 0, 0, 0);
    }
    __builtin_amdgcn_s_setprio(0);
    if (w8) asm volatile("s_waitcnt vmcnt(8)" ::: "memory");  // lands tile T+1; T+2,T+3 stay in flight
    BAR();
  };

  // main loop: full staging, counted vmcnt (never 0)
  for (int T = 0; T + 4 <= NT; ++T) tile(T, true, true);
  // drain once, then 3 resident tail tiles
  asm volatile("s_waitcnt vmcnt(0)" ::: "memory");
  BAR();
  for (int T = NT - 3; T < NT; ++T) tile(T, false, false);

  // ---- epilogue ----
  const int r0 = bm * 256 + wr + (gq << 2);
  const int c0 = bn * 256 + wc + fr;
#pragma unroll
  for (int m = 0; m < 8; ++m) {
    if constexpr (EPI == 0) {
#pragma unroll
      for (int j = 0; j < 4; ++j) {
        size_t ro = (size_t)(r0 + m * 16 + j) * ldc + c0;
#pragma unroll
        for (int n = 0; n < 4; ++n)
          C[ro + n * 16] = f2bf(acc[m][n][j]);
      }
    } else {
      // Fused activation: interleaved cols (2k = mag_k, 2k+1 = phase_k);
      // adjacent cols sit in adjacent lanes -> shfl_xor(1) pairs them.
#pragma unroll
      for (int n = 0; n < 4; ++n) {
        const int col = c0 + n * 16;
        const bool valid = col < ODIM;
        const float bs = valid ? bias[(col >> 1) + (col & 1) * KP] : 0.0f;
        const bool isPhase = (col & 1);
#pragma unroll
        for (int j = 0; j < 4; ++j) {
          float v = acc[m][n][j] + bs;
          float pv = __shfl_xor(v, 1);
          float hm = isPhase ? pv : v;
          float hp = isPhase ? v : pv;
          float mag = fminf(fast_exp(hm), 100.0f);
          float outv = isPhase ? mag * fast_sin(hp) : mag * fast_cos(hp);
          if (col < ncol)
            C[(size_t)(r0 + m * 16 + j) * ldc + col] = valid ? f2bf(outv) : (ushort)0;
        }
      }
    }
  }
}

// ---------------- overlap-add + envelope + crop (4 samples/thread) ----------------
// Interior envelope is exactly 1.5 (Hann^2 OLA at 75% overlap); edges computed inline.
__global__ void k_oa(const ushort* __restrict__ frames, float* __restrict__ out) {
  int u = blockIdx.x * 256 + threadIdx.x;       // 16 * 262144 groups of 4 samples
  int b  = u >> 18;
  int g  = u & 262143;
  int s  = (g << 2) + PADC;
  int t0 = s >> 8;
  int nb = s & 255;                             // <= 252, so the 4 samples share q-blocks
  float acc[4] = {0.f, 0.f, 0.f, 0.f};
  bool interior = (t0 >= 3) && (t0 < TFRM);
  float env[4];
#pragma unroll
  for (int j = 0; j < 4; ++j) env[j] = interior ? 1.5f : 0.0f;
#pragma unroll
  for (int q = 0; q < 4; ++q) {
    int t = t0 - q;
    if (t >= 0 && t < TFRM) {
      int n = nb + (q << 8);
      ushort4 v = *(const ushort4*)(frames + (((size_t)(b << 12) + t) << 10) + n);
      acc[0] += bf2f(v.x); acc[1] += bf2f(v.y); acc[2] += bf2f(v.z); acc[3] += bf2f(v.w);
      if (!interior) {
#pragma unroll
        for (int j = 0; j < 4; ++j) {
          float w = 0.5f - 0.5f * __builtin_amdgcn_cosf((float)(n + j) * (1.0f / 1024.0f));
          env[j] += w * w;
        }
      }
    }
  }
  float4 o;
  o.x = acc[0] / env[0]; o.y = acc[1] / env[1];
  o.z = acc[2] / env[2]; o.w = acc[3] / env[3];
  *(float4*)(out + (size_t)u * 4) = o;
}

// ---------------- launch ----------------
extern "C" void kernel_launch(void* const* d_in, const int* in_sizes, int n_in,
                              void* d_out, int out_size, void* d_ws, size_t ws_size,
                              hipStream_t stream) {
  const float* x    = (const float*)d_in[0];
  const float* W    = (const float*)d_in[1];
  const float* bias = (const float*)d_in[2];
  float* out = (float*)d_out;
  char* ws = (char*)d_ws;

  // ws layout (bytes):
  //   [0, 134217728)            x_bf16 (dead after GEMM1)  ALIASED WITH frames
  //   [134217728, 135528448)    Wp bf16 [1280][512] (column-permuted, zero-padded)
  //   [135528448, 137887744)    BasisT bf16 [1024][1152] (interleaved layout)
  //   [137887744, 288882688)    h bf16 [65536][1152] (post-activation)
  ushort* xbf    = (ushort*)(ws + 0);
  ushort* frames = (ushort*)(ws + 0);
  ushort* Wp     = (ushort*)(ws + 134217728);
  ushort* bas    = (ushort*)(ws + 135528448);
  ushort* h      = (ushort*)(ws + 137887744);

  k_prep_x<<<8192, 256, 0, stream>>>((const float4*)x, (ushort4*)xbf, (MROWS * DIM) / 4);
  k_prep_w<<<(WROWS * DIM) / 256, 256, 0, stream>>>(W, Wp);
  k_basis<<<NFFT, 256, 0, stream>>>(bas);

  // GEMM1 + fused activation: h[65536][<1152] = act( xbf . Wp^T + bias ), N padded to 1280
  k_gemm<1><<<(MROWS / 256) * (WROWS / 256), 512, 0, stream>>>(
      xbf, DIM, Wp, DIM, h, NPAD, WROWS / 256, DIM / 32, NPAD, bias);

  // GEMM2: frames[65536][1024] = h[65536][1152] . BasisT^T
  k_gemm<0><<<(MROWS / 256) * (NFFT / 256), 512, 0, stream>>>(
      h, NPAD, bas, NPAD, frames, NFFT, NFFT / 256, NPAD / 32, NFFT, nullptr);

  // overlap-add, envelope normalize, crop
  k_oa<<<(BATCH * OUTLEN) / 1024, 256, 0, stream>>>(frames, out);
}

// Round 6
// 376.551 us; speedup vs baseline: 4.9676x; 1.0014x over previous
//
#include <hip/hip_runtime.h>
#include <hip/hip_bf16.h>
#include <math.h>

// ---------------- constants ----------------
#define BATCH   16
#define TFRM    4096          // frames per batch (= L)
#define DIM     512
#define ODIM    1026
#define KP      513           // ODIM/2
#define NFFT    1024
#define HOP     256
#define PADC    384           // (WIN-HOP)/2
#define MROWS   (BATCH*TFRM)  // 65536
#define NPAD    1152          // h stride (= GEMM2 K), multiple of 32
#define WROWS   1280          // GEMM1 logical N, multiple of 256
#define OUTLEN  1048576       // per-batch output samples
#define TWO_PI_OVER_N 0.006135923151542565f  // 2*pi/1024
#define INV_TWO_PI    0.15915494309189535f   // 1/(2*pi)

typedef __bf16 bf16x8 __attribute__((ext_vector_type(8)));
typedef float  f32x4  __attribute__((ext_vector_type(4)));

__device__ __forceinline__ ushort f2bf(float f) {
  union { float f; unsigned u; } v; v.f = f;
  unsigned u = v.u;
  unsigned r = (u + 0x7FFFu + ((u >> 16) & 1u)) >> 16;
  return (ushort)r;
}
__device__ __forceinline__ float bf2f(ushort h) {
  union { unsigned u; float f; } v; v.u = ((unsigned)h) << 16;
  return v.f;
}
// HW transcendentals (single VALU op each; v_sin/v_cos take revolutions).
__device__ __forceinline__ float fast_sin(float x) { return __builtin_amdgcn_sinf(x * INV_TWO_PI); }
__device__ __forceinline__ float fast_cos(float x) { return __builtin_amdgcn_cosf(x * INV_TWO_PI); }
__device__ __forceinline__ float fast_exp(float x) { return __builtin_amdgcn_exp2f(x * 1.4426950408889634f); }

#define BAR() do { asm volatile("" ::: "memory"); __builtin_amdgcn_s_barrier(); \
                   asm volatile("" ::: "memory"); } while (0)

// ---------------- prep: x fp32 -> bf16 ----------------
__global__ void k_prep_x(const float4* __restrict__ x, ushort4* __restrict__ o, int n4) {
  int i = blockIdx.x * blockDim.x + threadIdx.x;
  int stride = gridDim.x * blockDim.x;
  for (; i < n4; i += stride) {
    float4 v = x[i];
    ushort4 r;
    r.x = f2bf(v.x); r.y = f2bf(v.y); r.z = f2bf(v.z); r.w = f2bf(v.w);
    o[i] = r;
  }
}

// ---------------- prep: W fp32 [1026][512] -> bf16 COLUMN-PERMUTED padded [1280][512]
// Row j (= h column j): j=2k -> orig mag row k; j=2k+1 -> orig phase row 513+k.
__global__ void k_prep_w(const float* __restrict__ W, ushort* __restrict__ o) {
  int i = blockIdx.x * 256 + threadIdx.x;          // over 1280*512
  if (i >= WROWS * DIM) return;
  int r = i >> 9;
  int c = i & 511;
  ushort v = 0;
  if (r < ODIM) {
    int orig = (r >> 1) + (r & 1) * KP;
    v = f2bf(W[orig * DIM + c]);
  }
  o[i] = v;
}

// ---------------- basis: BasisT[n][j] bf16, interleaved (a,b) layout, stride NPAD ----------------
// frames[n] = win[n]/1024 * ( a0 + a512*(-1)^n + 2*sum_{k=1}^{511}(a_k cos - b_k sin) )
__global__ void k_basis(ushort* __restrict__ bas) {
  int n = blockIdx.x;
  float wn = 0.5f - 0.5f * cosf((float)n * TWO_PI_OVER_N);
  float sc = wn * (1.0f / 1024.0f);
  for (int j = threadIdx.x; j < NPAD; j += 256) {
    float v = 0.0f;
    if (j < ODIM) {
      int k = j >> 1;
      int r = (k * n) & 1023;                      // exact integer phase reduction
      if ((j & 1) == 0) {
        float c = cosf((float)r * TWO_PI_OVER_N);
        v = ((k == 0 || k == 512) ? 1.0f : 2.0f) * c;
      } else if (k != 0 && k != 512) {
        v = -2.0f * sinf((float)r * TWO_PI_OVER_N);
      }
    }
    bas[n * NPAD + j] = f2bf(v * sc);
  }
}

// ---------------- GEMM: C[m][n] = sum_k A[m][k]*Bt[n][k]  (bf16 in, fp32 acc)
// 256x256 tile, BK=32, 8 waves (2M x 4N), 512 threads, ring of 4 LDS buffers.
// Cross-tile register pipeline: hot frags (aF0,aF1,bF0,bF1) of tile T+1 read at END of
// tile T (after counted vmcnt + barrier), remaining 8 reads issued in use-order at tile
// start so the compiler's counted lgkmcnt overlaps LDS drain with the MFMA cluster.
// One barrier per K-tile. Counted vmcnt (8 in steady state; 4/0 in tail), never an
// in-loop drain. Granule-XOR LDS swizzle (inverse-swizzled global source + swizzled
// ds_read) keeps bank conflicts at 0. XCD-chunked block swizzle for L2 locality.
// EPI=1: fused ISTFT-head activation on interleaved (mag,phase) columns.
template<int EPI>
__global__ __launch_bounds__(512, 2) void k_gemm(const ushort* __restrict__ A, int lda,
                                                 const ushort* __restrict__ Bt, int ldb,
                                                 ushort* __restrict__ C, int ldc,
                                                 int nbn, int NT, int ncol,
                                                 const float* __restrict__ bias) {
  // 4 bufs x (A 256x32 + B 256x32) ushorts = 128 KiB
  __shared__ ushort lds[4][2][8192];
  const int tid  = threadIdx.x;
  const int cpx  = gridDim.x >> 3;
  const int bid  = (blockIdx.x & 7) * cpx + (blockIdx.x >> 3);   // XCD-chunked
  const int bm   = bid / nbn;
  const int bn   = bid - bm * nbn;
  const int lane = tid & 63;
  const int wv   = tid >> 6;
  const int wr   = (wv >> 2) * 128;    // wave M-offset (2 M-halves)
  const int wc   = (wv & 3) * 64;      // wave N-offset (4 N-quarters)
  const int fr   = lane & 15;
  const int gq   = lane >> 4;          // K-granule of the fragment (0..3)

  // ---- staging (thread i covers granule i and i+512 of each 256x32 tile) ----
  // LDS written linearly by global_load_lds; swizzle realized by permuting the GLOBAL
  // source granule: gcol = (i&3) ^ ((i>>3)&3)  (= (i&3) ^ ((row>>1)&3)).
  const int swz  = ((tid & 3) ^ ((tid >> 3) & 3)) << 3;          // ushort offset
  const ushort* gA0 = A  + (size_t)(bm * 256 + (tid >> 2)) * lda + swz;
  const ushort* gA1 = gA0 + (size_t)128 * lda;
  const ushort* gB0 = Bt + (size_t)(bn * 256 + (tid >> 2)) * ldb + swz;
  const ushort* gB1 = gB0 + (size_t)128 * ldb;
  const int lofs = (tid & 448) * 8;    // wave-uniform LDS granule base (x8 ushorts)

  auto stage = [&](int S) {            // 4 loads, consecutive in vmcnt order
    ushort* dA = &lds[S & 3][0][0];
    ushort* dB = &lds[S & 3][1][0];
    __builtin_amdgcn_global_load_lds((const __attribute__((address_space(1))) void*)(gA0 + S * 32),
        (__attribute__((address_space(3))) void*)(dA + lofs), 16, 0, 0);
    __builtin_amdgcn_global_load_lds((const __attribute__((address_space(1))) void*)(gA1 + S * 32),
        (__attribute__((address_space(3))) void*)(dA + 4096 + lofs), 16, 0, 0);
    __builtin_amdgcn_global_load_lds((const __attribute__((address_space(1))) void*)(gB0 + S * 32),
        (__attribute__((address_space(3))) void*)(dB + lofs), 16, 0, 0);
    __builtin_amdgcn_global_load_lds((const __attribute__((address_space(1))) void*)(gB1 + S * 32),
        (__attribute__((address_space(3))) void*)(dB + 4096 + lofs), 16, 0, 0);
  };
  // swizzled fragment read: logical (row, gq) lives at physical granule gq ^ ((row>>1)&3)
  auto frag = [&](const ushort* lb, int row) -> bf16x8 {
    return *(const bf16x8*)(lb + row * 32 + ((gq ^ ((row >> 1) & 3)) << 3));
  };

  f32x4 acc[8][4] = {};
  bf16x8 aF[8], bF[4];

  // ---- prologue: stage tiles 0,1,2 (12 loads); land tile 0; hot-read tile 0 ----
  stage(0); stage(1); stage(2);
  asm volatile("s_waitcnt vmcnt(8)" ::: "memory");
  BAR();
  {
    const ushort* lA = &lds[0][0][0];
    const ushort* lB = &lds[0][1][0];
    aF[0] = frag(lA, wr + fr);      aF[1] = frag(lA, wr + 16 + fr);
    bF[0] = frag(lB, wc + fr);      bF[1] = frag(lB, wc + 16 + fr);
  }

  auto body = [&](int T, bool stg, int wn) {
    const ushort* lA = &lds[T & 3][0][0];
    const ushort* lB = &lds[T & 3][1][0];
    // remaining reads of tile T, in exact use-order (compiler emits counted lgkmcnt)
#pragma unroll
    for (int m = 2; m < 8; ++m) aF[m] = frag(lA, wr + m * 16 + fr);
    bF[2] = frag(lB, wc + 32 + fr);
    bF[3] = frag(lB, wc + 48 + fr);
    if (stg) stage(T + 3);
    __builtin_amdgcn_s_setprio(1);
#pragma unroll
    for (int m = 0; m < 8; ++m) {   // first half: needs only hot frags + aF[m] as they land
      acc[m][0] = __builtin_amdgcn_mfma_f32_16x16x32_bf16(aF[m], bF[0], acc[m][0], 0, 0, 0);
      acc[m][1] = __builtin_amdgcn_mfma_f32_16x16x32_bf16(aF[m], bF[1], acc[m][1], 0, 0, 0);
    }
#pragma unroll
    for (int m = 0; m < 8; ++m) {   // second half: bF[2],bF[3] have had max time to land
      acc[m][2] = __builtin_amdgcn_mfma_f32_16x16x32_bf16(aF[m], bF[2], acc[m][2], 0, 0, 0);
      acc[m][3] = __builtin_amdgcn_mfma_f32_16x16x32_bf16(aF[m], bF[3], acc[m][3], 0, 0, 0);
    }
    __builtin_amdgcn_s_setprio(0);
    // counted vmcnt: land tile T+1 (leave younger tiles in flight)
    if (wn == 8)      asm volatile("s_waitcnt vmcnt(8)" ::: "memory");
    else if (wn == 4) asm volatile("s_waitcnt vmcnt(4)" ::: "memory");
    else if (wn == 0) asm volatile("s_waitcnt vmcnt(0)" ::: "memory");
    BAR();   // all waves' T+1 loads landed -> hot reads safe (staged cross-wave)
    if (T + 1 < NT) {
      const ushort* nA = &lds[(T + 1) & 3][0][0];
      const ushort* nB = &lds[(T + 1) & 3][1][0];
      aF[0] = frag(nA, wr + fr);      aF[1] = frag(nA, wr + 16 + fr);
      bF[0] = frag(nB, wc + fr);      bF[1] = frag(nB, wc + 16 + fr);
    }
  };

  for (int T = 0; T < NT - 3; ++T) body(T, true, 8);   // stages T+3 in [3, NT-1]
  body(NT - 3, false, 4);
  body(NT - 2, false, 0);
  body(NT - 1, false, -1);

  // ---- epilogue ----
  const int r0 = bm * 256 + wr + (gq << 2);
  const int c0 = bn * 256 + wc + fr;
#pragma unroll
  for (int m = 0; m < 8; ++m) {
    if constexpr (EPI == 0) {
#pragma unroll
      for (int j = 0; j < 4; ++j) {
        size_t ro = (size_t)(r0 + m * 16 + j) * ldc + c0;
#pragma unroll
        for (int n = 0; n < 4; ++n)
          C[ro + n * 16] = f2bf(acc[m][n][j]);
      }
    } else {
      // Fused activation: interleaved cols (2k = mag_k, 2k+1 = phase_k);
      // adjacent cols sit in adjacent lanes -> shfl_xor(1) pairs them.
#pragma unroll
      for (int n = 0; n < 4; ++n) {
        const int col = c0 + n * 16;
        const bool valid = col < ODIM;
        const float bs = valid ? bias[(col >> 1) + (col & 1) * KP] : 0.0f;
        const bool isPhase = (col & 1);
#pragma unroll
        for (int j = 0; j < 4; ++j) {
          float v = acc[m][n][j] + bs;
          float pv = __shfl_xor(v, 1);
          float hm = isPhase ? pv : v;
          float hp = isPhase ? v : pv;
          float mag = fminf(fast_exp(hm), 100.0f);
          float outv = isPhase ? mag * fast_sin(hp) : mag * fast_cos(hp);
          if (col < ncol)
            C[(size_t)(r0 + m * 16 + j) * ldc + col] = valid ? f2bf(outv) : (ushort)0;
        }
      }
    }
  }
}

// ---------------- overlap-add + envelope + crop (4 samples/thread) ----------------
// Interior envelope is exactly 1.5 (Hann^2 OLA at 75% overlap); edges computed inline.
__global__ void k_oa(const ushort* __restrict__ frames, float* __restrict__ out) {
  int u = blockIdx.x * 256 + threadIdx.x;       // 16 * 262144 groups of 4 samples
  int b  = u >> 18;
  int g  = u & 262143;
  int s  = (g << 2) + PADC;
  int t0 = s >> 8;
  int nb = s & 255;                             // <= 252, so the 4 samples share q-blocks
  float acc[4] = {0.f, 0.f, 0.f, 0.f};
  bool interior = (t0 >= 3) && (t0 < TFRM);
  float env[4];
#pragma unroll
  for (int j = 0; j < 4; ++j) env[j] = interior ? 1.5f : 0.0f;
#pragma unroll
  for (int q = 0; q < 4; ++q) {
    int t = t0 - q;
    if (t >= 0 && t < TFRM) {
      int n = nb + (q << 8);
      ushort4 v = *(const ushort4*)(frames + (((size_t)(b << 12) + t) << 10) + n);
      acc[0] += bf2f(v.x); acc[1] += bf2f(v.y); acc[2] += bf2f(v.z); acc[3] += bf2f(v.w);
      if (!interior) {
#pragma unroll
        for (int j = 0; j < 4; ++j) {
          float w = 0.5f - 0.5f * __builtin_amdgcn_cosf((float)(n + j) * (1.0f / 1024.0f));
          env[j] += w * w;
        }
      }
    }
  }
  float4 o;
  o.x = acc[0] / env[0]; o.y = acc[1] / env[1];
  o.z = acc[2] / env[2]; o.w = acc[3] / env[3];
  *(float4*)(out + (size_t)u * 4) = o;
}

// ---------------- launch ----------------
extern "C" void kernel_launch(void* const* d_in, const int* in_sizes, int n_in,
                              void* d_out, int out_size, void* d_ws, size_t ws_size,
                              hipStream_t stream) {
  const float* x    = (const float*)d_in[0];
  const float* W    = (const float*)d_in[1];
  const float* bias = (const float*)d_in[2];
  float* out = (float*)d_out;
  char* ws = (char*)d_ws;

  // ws layout (bytes):
  //   [0, 134217728)            x_bf16 (dead after GEMM1)  ALIASED WITH frames
  //   [134217728, 135528448)    Wp bf16 [1280][512] (column-permuted, zero-padded)
  //   [135528448, 137887744)    BasisT bf16 [1024][1152] (interleaved layout)
  //   [137887744, 288882688)    h bf16 [65536][1152] (post-activation)
  ushort* xbf    = (ushort*)(ws + 0);
  ushort* frames = (ushort*)(ws + 0);
  ushort* Wp     = (ushort*)(ws + 134217728);
  ushort* bas    = (ushort*)(ws + 135528448);
  ushort* h      = (ushort*)(ws + 137887744);

  k_prep_x<<<8192, 256, 0, stream>>>((const float4*)x, (ushort4*)xbf, (MROWS * DIM) / 4);
  k_prep_w<<<(WROWS * DIM) / 256, 256, 0, stream>>>(W, Wp);
  k_basis<<<NFFT, 256, 0, stream>>>(bas);

  // GEMM1 + fused activation: h[65536][<1152] = act( xbf . Wp^T + bias ), N padded to 1280
  k_gemm<1><<<(MROWS / 256) * (WROWS / 256), 512, 0, stream>>>(
      xbf, DIM, Wp, DIM, h, NPAD, WROWS / 256, DIM / 32, NPAD, bias);

  // GEMM2: frames[65536][1024] = h[65536][1152] . BasisT^T
  k_gemm<0><<<(MROWS / 256) * (NFFT / 256), 512, 0, stream>>>(
      h, NPAD, bas, NPAD, frames, NFFT, NFFT / 256, NPAD / 32, NFFT, nullptr);

  // overlap-add, envelope normalize, crop
  k_oa<<<(BATCH * OUTLEN) / 1024, 256, 0, stream>>>(frames, out);
}